// Round 3
// baseline (138.695 us; speedup 1.0000x reference)
//
#include <hip/hip_runtime.h>

typedef unsigned short u16;
typedef __bf16 bf16x8 __attribute__((ext_vector_type(8)));
typedef float f32x4 __attribute__((ext_vector_type(4)));
typedef u16 u16x4 __attribute__((ext_vector_type(4)));
typedef u16 u16x8 __attribute__((ext_vector_type(8)));

#define EPS 1e-5f

__device__ __forceinline__ u16 f2bf(float f) {
  unsigned u = __builtin_bit_cast(unsigned, f);
  u += 0x7FFFu + ((u >> 16) & 1u);   // RNE
  return (u16)(u >> 16);
}
__device__ __forceinline__ float bf2f(u16 h) {
  unsigned u = ((unsigned)h) << 16;
  return __builtin_bit_cast(float, u);
}

// ---------------- weight prep: fold BN scale into bf16 weights ----------------
__global__ void prep_weights(
    const float* __restrict__ wa, const float* __restrict__ g1, const float* __restrict__ b1,
    const float* __restrict__ m1, const float* __restrict__ v1,
    const float* __restrict__ w1, const float* __restrict__ g2, const float* __restrict__ b2,
    const float* __restrict__ m2, const float* __restrict__ v2,
    const float* __restrict__ w2,
    u16* __restrict__ wa_o, u16* __restrict__ w1_o, u16* __restrict__ w2_o,
    float* __restrict__ bias1, float* __restrict__ bias2) {
  int t = blockIdx.x * 256 + threadIdx.x;
  if (t < 256 * 256) {
    int m = t >> 8;
    float s = g1[m] / sqrtf(v1[m] + EPS);
    wa_o[t] = f2bf(wa[t] * s);
  }
  if (t < 128 * 256) {
    int m = t >> 8;
    float s = g2[m] / sqrtf(v2[m] + EPS);
    w1_o[t] = f2bf(w1[t] * s);
  }
  if (t < 256 * 128) w2_o[t] = f2bf(w2[t]);
  if (t < 256) bias1[t] = b1[t] - m1[t] * (g1[t] / sqrtf(v1[t] + EPS));
  if (t < 128) bias2[t] = b2[t] - m2[t] * (g2[t] / sqrtf(v2[t] + EPS));
}

// ---------------- grouped 3x3 conv + SiLU -> s[b][q][p] ----------------
// grid = (band=4, q=64, b=16) = 4096 blocks, 256 threads. One barrier per block.
__global__ __launch_bounds__(256) void gconv_kernel(
    const float* __restrict__ xl, const float* __restrict__ w1,
    float* __restrict__ sbuf) {
  __shared__ float tile[4][18][66];
  const int tid = threadIdx.x;
  const int band = blockIdx.x;   // 16-row band
  const int q = blockIdx.y;
  const int b = blockIdx.z;
  const float* xb = xl + ((size_t)b * 256 + 4 * q) * 4096;
  for (int i = tid; i < 4 * 18 * 66; i += 256) {
    int ci = i / (18 * 66);
    int rem = i - ci * (18 * 66);
    int r = rem / 66, c = rem - r * 66;
    int gy = band * 16 - 1 + r, gx = c - 1;
    float v = 0.f;
    if ((unsigned)gy < 64u && (unsigned)gx < 64u)
      v = xb[(size_t)ci * 4096 + gy * 64 + gx];
    tile[ci][r][c] = v;
  }
  float wq[36];
#pragma unroll
  for (int i = 0; i < 36; ++i) wq[i] = w1[q * 36 + i];
  __syncthreads();
  const int c = tid & 63, r0 = tid >> 6;
  float* sp = sbuf + ((size_t)(b * 64 + q)) * 4096 + band * 1024;
#pragma unroll
  for (int k = 0; k < 4; ++k) {
    int r = r0 * 4 + k;
    float s = 0.f;
#pragma unroll
    for (int ci = 0; ci < 4; ++ci)
#pragma unroll
      for (int dy = 0; dy < 3; ++dy)
#pragma unroll
        for (int dx = 0; dx < 3; ++dx)
          s += wq[ci * 9 + dy * 3 + dx] * tile[ci][r + dy][c + dx];
    sp[r * 64 + c] = s / (1.f + __expf(-s));  // SiLU
  }
}

// ---------------- 1x1 conv over groups -> sample coords ----------------
__global__ __launch_bounds__(256) void coords_kernel(
    const float* __restrict__ sbuf, const float* __restrict__ w2,
    const float* __restrict__ b2, float* __restrict__ coords) {
  __shared__ float sw2[128];
  const int tid = threadIdx.x;
  if (tid < 128) sw2[tid] = w2[tid];
  __syncthreads();
  const int b = blockIdx.y;
  const int p = blockIdx.x * 256 + tid;
  const float* sp = sbuf + (size_t)b * 64 * 4096 + p;
  float ax = 0.f, ay = 0.f;
#pragma unroll 8
  for (int q = 0; q < 64; ++q) {
    float v = sp[(size_t)q * 4096];
    ax += sw2[q] * v;
    ay += sw2[64 + q] * v;
  }
  int y = p >> 6, x = p & 63;
  float ix = (64.f / 63.f) * (float)x + ax + b2[0] - 0.5f;
  float iy = (64.f / 63.f) * (float)y + ay + b2[1] - 0.5f;
  ((float2*)coords)[(size_t)b * 4096 + p] = make_float2(ix, iy);
}

// ---------------- templated MFMA GEMM ----------------
// BM=BN=128, BK=32, 4 waves, wave = 64x64 quadrant (4x4 frags of 16x16x32).
// A: [Mtot][K] bf16 weights. B: f32 channel-major [K][4096] (transpose in reg)
//    or bf16 PIXEL-major [4096][K] (direct u16x8 -> LDS [n][k]).
// Intermediates g/h are PIXEL-major: out[b][p][CT] bf16.
// EPI 0: +bias -> g[p][256]. EPI 1: +bias, GELU -> h[p][128].
// EPI 2: bilinear-sample(g[p][c]) + acc, SiLU -> out f32 [c][p].
template <int K, bool B_PIXMAJOR_BF16, int EPI>
__global__ __launch_bounds__(256, 2) void gemm_k(
    const u16* __restrict__ A, const void* __restrict__ Bsrc,
    u16* __restrict__ OutBf, const float* __restrict__ bias,
    const u16* __restrict__ g, const float* __restrict__ coords,
    float* __restrict__ out_f) {
  __shared__ u16 Al[128][40];  // 32 data + 8 pad (row = 80B)
  __shared__ u16 Bl[128][40];  // [n][k]
  const int tid = threadIdx.x;
  const int b = blockIdx.z;
  const int n0 = blockIdx.x * 128;
  const int m0 = blockIdx.y * 128;
  const int wave = tid >> 6, lane = tid & 63;
  const int wr = wave >> 1, wc = wave & 1;
  const int lr = lane & 15, kg = lane >> 4;

  f32x4 acc[4][4] = {};

  const float* Bf = (const float*)Bsrc + (size_t)b * K * 4096;
  const u16* Bh = (const u16*)Bsrc + (size_t)b * 4096 * K;  // pixel-major

  for (int kt = 0; kt < K / 32; ++kt) {
    // ---- stage A ----
#pragma unroll
    for (int c = 0; c < 2; ++c) {
      int ch = tid + c * 256;
      int m = ch >> 2, pos = (ch & 3) * 8;
      u16x8 v = *(const u16x8*)(A + (size_t)(m0 + m) * K + kt * 32 + pos);
      *(u16x8*)&Al[m][pos] = v;
    }
    // ---- stage B ----
    if (B_PIXMAJOR_BF16) {
      // h[p][k]: rows are already [n][k] -> straight vector copy
#pragma unroll
      for (int c = 0; c < 2; ++c) {
        int idx = tid + c * 256;          // 0..511
        int pl = idx >> 2, kq = idx & 3;  // pl 0..127, kq 0..3
        u16x8 v = *(const u16x8*)(Bh + (size_t)(n0 + pl) * K + kt * 32 + kq * 8);
        *(u16x8*)&Bl[pl][kq * 8] = v;
      }
    } else {
      // f32 channel-major [K][4096]: 4x4 micro-tile transpose in registers
      int nq = tid & 31, kq = tid >> 5;
      int kb = kt * 32 + kq * 4;
      int nb = n0 + nq * 4;
      f32x4 r[4];
#pragma unroll
      for (int i = 0; i < 4; ++i)
        r[i] = *(const f32x4*)(Bf + (size_t)(kb + i) * 4096 + nb);
#pragma unroll
      for (int j = 0; j < 4; ++j) {
        u16x4 w = {f2bf(r[0][j]), f2bf(r[1][j]), f2bf(r[2][j]), f2bf(r[3][j])};
        *(u16x4*)&Bl[nq * 4 + j][kq * 4] = w;
      }
    }
    __syncthreads();
    bf16x8 af[4], bfr[4];
#pragma unroll
    for (int i = 0; i < 4; ++i) {
      af[i] = *(const bf16x8*)&Al[wr * 64 + i * 16 + lr][kg * 8];
      bfr[i] = *(const bf16x8*)&Bl[wc * 64 + i * 16 + lr][kg * 8];
    }
#pragma unroll
    for (int i = 0; i < 4; ++i)
#pragma unroll
      for (int j = 0; j < 4; ++j)
        acc[i][j] = __builtin_amdgcn_mfma_f32_16x16x32_bf16(af[i], bfr[j], acc[i][j], 0, 0, 0);
    __syncthreads();
  }

  // ---- epilogue ----
  if constexpr (EPI == 0 || EPI == 1) {
    const int CT = (EPI == 0) ? 256 : 128;  // channels per pixel row
    u16* O = OutBf + (size_t)b * 4096 * CT;
#pragma unroll
    for (int i = 0; i < 4; ++i) {
      int rb = m0 + wr * 64 + i * 16 + kg * 4;
      f32x4 b4 = *(const f32x4*)(bias + rb);
#pragma unroll
      for (int j = 0; j < 4; ++j) {
        int col = n0 + wc * 64 + j * 16 + lr;
        u16x4 w;
#pragma unroll
        for (int e = 0; e < 4; ++e) {
          float v = acc[i][j][e] + b4[e];
          if (EPI == 1) v = 0.5f * v * (1.f + erff(v * 0.70710678118f));  // exact GELU
          w[e] = f2bf(v);
        }
        *(u16x4*)(O + (size_t)col * CT + rb) = w;  // pixel-major, 8B store
      }
    }
  } else {
    const u16* gb = g + (size_t)b * 4096 * 256;  // pixel-major g
    float* Ob = out_f + (size_t)b * 256 * 4096;
#pragma unroll
    for (int j = 0; j < 4; ++j) {
      int col = n0 + wc * 64 + j * 16 + lr;
      float2 cd = ((const float2*)coords)[(size_t)b * 4096 + col];
      float ix = cd.x, iy = cd.y;
      float x0f = floorf(ix), y0f = floorf(iy);
      int x0 = (int)x0f, y0 = (int)y0f;
      float wx1 = ix - x0f, wx0 = 1.f - wx1;
      float wy1 = iy - y0f, wy0 = 1.f - wy1;
      bool vx0 = (unsigned)x0 < 64u, vx1 = (unsigned)(x0 + 1) < 64u;
      bool vy0 = (unsigned)y0 < 64u, vy1 = (unsigned)(y0 + 1) < 64u;
      int x0c = min(max(x0, 0), 63), x1c = min(max(x0 + 1, 0), 63);
      int y0c = min(max(y0, 0), 63), y1c = min(max(y0 + 1, 0), 63);
      float w00 = (vx0 && vy0) ? wx0 * wy0 : 0.f;
      float w10 = (vx1 && vy0) ? wx1 * wy0 : 0.f;
      float w01 = (vx0 && vy1) ? wx0 * wy1 : 0.f;
      float w11 = (vx1 && vy1) ? wx1 * wy1 : 0.f;
      const u16* r00 = gb + ((size_t)(y0c * 64 + x0c)) * 256;
      const u16* r10 = gb + ((size_t)(y0c * 64 + x1c)) * 256;
      const u16* r01 = gb + ((size_t)(y1c * 64 + x0c)) * 256;
      const u16* r11 = gb + ((size_t)(y1c * 64 + x1c)) * 256;
#pragma unroll
      for (int i = 0; i < 4; ++i) {
        int rb = m0 + wr * 64 + i * 16 + kg * 4;
        u16x4 a00 = *(const u16x4*)(r00 + rb);
        u16x4 a10 = *(const u16x4*)(r10 + rb);
        u16x4 a01 = *(const u16x4*)(r01 + rb);
        u16x4 a11 = *(const u16x4*)(r11 + rb);
#pragma unroll
        for (int e = 0; e < 4; ++e) {
          float samp = w00 * bf2f(a00[e]) + w10 * bf2f(a10[e]) +
                       w01 * bf2f(a01[e]) + w11 * bf2f(a11[e]);
          float v = samp + acc[i][j][e];
          Ob[(size_t)(rb + e) * 4096 + col] = v / (1.f + __expf(-v));  // SiLU
        }
      }
    }
  }
}

// ---------------- launch ----------------
extern "C" void kernel_launch(void* const* d_in, const int* in_sizes, int n_in,
                              void* d_out, int out_size, void* d_ws, size_t ws_size,
                              hipStream_t stream) {
  const float* x_local = (const float*)d_in[0];
  const float* x_guide = (const float*)d_in[1];
  const float* w_align = (const float*)d_in[2];
  const float* bn1_g = (const float*)d_in[3];
  const float* bn1_b = (const float*)d_in[4];
  const float* bn1_m = (const float*)d_in[5];
  const float* bn1_v = (const float*)d_in[6];
  const float* w_off1 = (const float*)d_in[7];
  const float* w_off2 = (const float*)d_in[8];
  const float* b_off2 = (const float*)d_in[9];
  const float* w_mlp1 = (const float*)d_in[10];
  const float* bn2_g = (const float*)d_in[11];
  const float* bn2_b = (const float*)d_in[12];
  const float* bn2_m = (const float*)d_in[13];
  const float* bn2_v = (const float*)d_in[14];
  const float* w_mlp2 = (const float*)d_in[15];

  char* ws = (char*)d_ws;
  u16* wa_bf = (u16*)(ws + 0);              // 131072
  u16* w1_bf = (u16*)(ws + 131072);         // 65536
  u16* w2_bf = (u16*)(ws + 196608);         // 65536
  float* bias1 = (float*)(ws + 262144);
  float* bias2 = (float*)(ws + 263168);
  float* coords = (float*)(ws + 263680);    // 524288
  u16* gbuf = (u16*)(ws + 787968);          // 16*4096*256*2 = 33554432 (pixel-major)
  u16* hbuf = (u16*)(ws + 34342400);        // 16*4096*128*2 = 16777216 (pixel-major)
  // sbuf aliases gbuf's region (consumed by coords_kernel before gemm EPI0 writes gbuf)
  float* sbuf = (float*)gbuf;

  prep_weights<<<256, 256, 0, stream>>>(
      w_align, bn1_g, bn1_b, bn1_m, bn1_v,
      w_mlp1, bn2_g, bn2_b, bn2_m, bn2_v, w_mlp2,
      wa_bf, w1_bf, w2_bf, bias1, bias2);

  gconv_kernel<<<dim3(4, 64, 16), 256, 0, stream>>>(x_local, w_off1, sbuf);

  coords_kernel<<<dim3(16, 16), 256, 0, stream>>>(sbuf, w_off2, b_off2, coords);

  // g = BN1(W_align @ x_guide)  -> pixel-major bf16
  gemm_k<256, false, 0><<<dim3(32, 2, 16), 256, 0, stream>>>(
      wa_bf, x_guide, gbuf, bias1, nullptr, nullptr, nullptr);

  // h = GELU(BN2(W1 @ x_local)) -> pixel-major bf16
  gemm_k<256, false, 1><<<dim3(32, 1, 16), 256, 0, stream>>>(
      w1_bf, x_local, hbuf, bias2, nullptr, nullptr, nullptr);

  // out = SiLU(sample(g) + W2 @ h) [f32 channel-major]
  gemm_k<128, true, 2><<<dim3(32, 2, 16), 256, 0, stream>>>(
      w2_bf, hbuf, nullptr, nullptr, gbuf, coords, (float*)d_out);
}

// Round 4
// 138.313 us; speedup vs baseline: 1.0028x; 1.0028x over previous
//
#include <hip/hip_runtime.h>

typedef unsigned short u16;
typedef __bf16 bf16x8 __attribute__((ext_vector_type(8)));
typedef float f32x4 __attribute__((ext_vector_type(4)));
typedef u16 u16x4 __attribute__((ext_vector_type(4)));
typedef u16 u16x8 __attribute__((ext_vector_type(8)));

#define EPS 1e-5f

__device__ __forceinline__ u16 f2bf(float f) {
  unsigned u = __builtin_bit_cast(unsigned, f);
  u += 0x7FFFu + ((u >> 16) & 1u);   // RNE
  return (u16)(u >> 16);
}
__device__ __forceinline__ float bf2f(u16 h) {
  unsigned u = ((unsigned)h) << 16;
  return __builtin_bit_cast(float, u);
}

// ---------------- weight prep: fold BN scale into bf16 weights ----------------
__global__ void prep_weights(
    const float* __restrict__ wa, const float* __restrict__ g1, const float* __restrict__ b1,
    const float* __restrict__ m1, const float* __restrict__ v1,
    const float* __restrict__ w1, const float* __restrict__ g2, const float* __restrict__ b2,
    const float* __restrict__ m2, const float* __restrict__ v2,
    const float* __restrict__ w2,
    u16* __restrict__ wa_o, u16* __restrict__ w1_o, u16* __restrict__ w2_o,
    float* __restrict__ bias1, float* __restrict__ bias2) {
  int t = blockIdx.x * 256 + threadIdx.x;
  if (t < 256 * 256) {
    int m = t >> 8;
    float s = g1[m] / sqrtf(v1[m] + EPS);
    wa_o[t] = f2bf(wa[t] * s);
  }
  if (t < 128 * 256) {
    int m = t >> 8;
    float s = g2[m] / sqrtf(v2[m] + EPS);
    w1_o[t] = f2bf(w1[t] * s);
  }
  if (t < 256 * 128) w2_o[t] = f2bf(w2[t]);
  if (t < 256) bias1[t] = b1[t] - m1[t] * (g1[t] / sqrtf(v1[t] + EPS));
  if (t < 128) bias2[t] = b2[t] - m2[t] * (g2[t] / sqrtf(v2[t] + EPS));
}

// ---------------- grouped 3x3 conv + SiLU -> s[b][q][p] ----------------
// grid = (band=4, q=64, b=16) = 4096 blocks, 256 threads. One barrier per block.
__global__ __launch_bounds__(256) void gconv_kernel(
    const float* __restrict__ xl, const float* __restrict__ w1,
    float* __restrict__ sbuf) {
  __shared__ float tile[4][18][66];
  const int tid = threadIdx.x;
  const int band = blockIdx.x;   // 16-row band
  const int q = blockIdx.y;
  const int b = blockIdx.z;
  const float* xb = xl + ((size_t)b * 256 + 4 * q) * 4096;
  for (int i = tid; i < 4 * 18 * 66; i += 256) {
    int ci = i / (18 * 66);
    int rem = i - ci * (18 * 66);
    int r = rem / 66, c = rem - r * 66;
    int gy = band * 16 - 1 + r, gx = c - 1;
    float v = 0.f;
    if ((unsigned)gy < 64u && (unsigned)gx < 64u)
      v = xb[(size_t)ci * 4096 + gy * 64 + gx];
    tile[ci][r][c] = v;
  }
  float wq[36];
#pragma unroll
  for (int i = 0; i < 36; ++i) wq[i] = w1[q * 36 + i];
  __syncthreads();
  const int c = tid & 63, r0 = tid >> 6;
  float* sp = sbuf + ((size_t)(b * 64 + q)) * 4096 + band * 1024;
#pragma unroll
  for (int k = 0; k < 4; ++k) {
    int r = r0 * 4 + k;
    float s = 0.f;
#pragma unroll
    for (int ci = 0; ci < 4; ++ci)
#pragma unroll
      for (int dy = 0; dy < 3; ++dy)
#pragma unroll
        for (int dx = 0; dx < 3; ++dx)
          s += wq[ci * 9 + dy * 3 + dx] * tile[ci][r + dy][c + dx];
    sp[r * 64 + c] = s / (1.f + __expf(-s));  // SiLU
  }
}

// ---------------- 1x1 conv over groups -> sample coords ----------------
__global__ __launch_bounds__(256) void coords_kernel(
    const float* __restrict__ sbuf, const float* __restrict__ w2,
    const float* __restrict__ b2, float* __restrict__ coords) {
  __shared__ float sw2[128];
  const int tid = threadIdx.x;
  if (tid < 128) sw2[tid] = w2[tid];
  __syncthreads();
  const int b = blockIdx.y;
  const int p = blockIdx.x * 256 + tid;
  const float* sp = sbuf + (size_t)b * 64 * 4096 + p;
  float ax = 0.f, ay = 0.f;
#pragma unroll 8
  for (int q = 0; q < 64; ++q) {
    float v = sp[(size_t)q * 4096];
    ax += sw2[q] * v;
    ay += sw2[64 + q] * v;
  }
  int y = p >> 6, x = p & 63;
  float ix = (64.f / 63.f) * (float)x + ax + b2[0] - 0.5f;
  float iy = (64.f / 63.f) * (float)y + ay + b2[1] - 0.5f;
  ((float2*)coords)[(size_t)b * 4096 + p] = make_float2(ix, iy);
}

// ---------------- templated MFMA GEMM ----------------
// BM=BN=128, BK=32, 4 waves, wave = 64x64 quadrant (4x4 frags of 16x16x32).
// A: [Mtot][K] bf16 weights. B: f32 channel-major [K][4096] (transpose in reg)
//    or bf16 PIXEL-major [4096][K] (direct u16x8 -> LDS [n][k]).
// Intermediates g/h are PIXEL-major: out[b][p][CT] bf16.
// EPI 0: +bias -> g[p][256]. EPI 1: +bias, GELU -> h[p][128].
// EPI 2: bilinear-sample(g[p][c]) + acc, SiLU -> out f32 [c][p].
template <int K, bool B_PIXMAJOR_BF16, int EPI>
__global__ __launch_bounds__(256, 2) void gemm_k(
    const u16* __restrict__ A, const void* __restrict__ Bsrc,
    u16* __restrict__ OutBf, const float* __restrict__ bias,
    const u16* __restrict__ g, const float* __restrict__ coords,
    float* __restrict__ out_f) {
  __shared__ u16 Al[128][40];  // 32 data + 8 pad (row = 80B)
  __shared__ u16 Bl[128][40];  // [n][k]
  const int tid = threadIdx.x;
  const int b = blockIdx.z;
  const int n0 = blockIdx.x * 128;
  const int m0 = blockIdx.y * 128;
  const int wave = tid >> 6, lane = tid & 63;
  const int wr = wave >> 1, wc = wave & 1;
  const int lr = lane & 15, kg = lane >> 4;

  f32x4 acc[4][4] = {};

  const float* Bf = (const float*)Bsrc + (size_t)b * K * 4096;
  const u16* Bh = (const u16*)Bsrc + (size_t)b * 4096 * K;  // pixel-major

  for (int kt = 0; kt < K / 32; ++kt) {
    // ---- stage A ----
#pragma unroll
    for (int c = 0; c < 2; ++c) {
      int ch = tid + c * 256;
      int m = ch >> 2, pos = (ch & 3) * 8;
      u16x8 v = *(const u16x8*)(A + (size_t)(m0 + m) * K + kt * 32 + pos);
      *(u16x8*)&Al[m][pos] = v;
    }
    // ---- stage B ----
    if (B_PIXMAJOR_BF16) {
      // h[p][k]: rows are already [n][k] -> straight vector copy
#pragma unroll
      for (int c = 0; c < 2; ++c) {
        int idx = tid + c * 256;          // 0..511
        int pl = idx >> 2, kq = idx & 3;  // pl 0..127, kq 0..3
        u16x8 v = *(const u16x8*)(Bh + (size_t)(n0 + pl) * K + kt * 32 + kq * 8);
        *(u16x8*)&Bl[pl][kq * 8] = v;
      }
    } else {
      // f32 channel-major [K][4096]: 4x4 micro-tile transpose in registers
      int nq = tid & 31, kq = tid >> 5;
      int kb = kt * 32 + kq * 4;
      int nb = n0 + nq * 4;
      f32x4 r[4];
#pragma unroll
      for (int i = 0; i < 4; ++i)
        r[i] = *(const f32x4*)(Bf + (size_t)(kb + i) * 4096 + nb);
#pragma unroll
      for (int j = 0; j < 4; ++j) {
        u16x4 w = {f2bf(r[0][j]), f2bf(r[1][j]), f2bf(r[2][j]), f2bf(r[3][j])};
        *(u16x4*)&Bl[nq * 4 + j][kq * 4] = w;
      }
    }
    __syncthreads();
    bf16x8 af[4], bfr[4];
#pragma unroll
    for (int i = 0; i < 4; ++i) {
      af[i] = *(const bf16x8*)&Al[wr * 64 + i * 16 + lr][kg * 8];
      bfr[i] = *(const bf16x8*)&Bl[wc * 64 + i * 16 + lr][kg * 8];
    }
#pragma unroll
    for (int i = 0; i < 4; ++i)
#pragma unroll
      for (int j = 0; j < 4; ++j)
        acc[i][j] = __builtin_amdgcn_mfma_f32_16x16x32_bf16(af[i], bfr[j], acc[i][j], 0, 0, 0);
    __syncthreads();
  }

  // ---- epilogue ----
  if constexpr (EPI == 0 || EPI == 1) {
    const int CT = (EPI == 0) ? 256 : 128;  // channels per pixel row
    u16* O = OutBf + (size_t)b * 4096 * CT;
#pragma unroll
    for (int i = 0; i < 4; ++i) {
      int rb = m0 + wr * 64 + i * 16 + kg * 4;
      f32x4 b4 = *(const f32x4*)(bias + rb);
#pragma unroll
      for (int j = 0; j < 4; ++j) {
        int col = n0 + wc * 64 + j * 16 + lr;
        u16x4 w;
#pragma unroll
        for (int e = 0; e < 4; ++e) {
          float v = acc[i][j][e] + b4[e];
          if (EPI == 1) v = 0.5f * v * (1.f + erff(v * 0.70710678118f));  // exact GELU
          w[e] = f2bf(v);
        }
        *(u16x4*)(O + (size_t)col * CT + rb) = w;  // pixel-major, 8B store
      }
    }
  } else {
    const u16* gb = g + (size_t)b * 4096 * 256;  // pixel-major g
    float* Ob = out_f + (size_t)b * 256 * 4096;
#pragma unroll
    for (int j = 0; j < 4; ++j) {
      int col = n0 + wc * 64 + j * 16 + lr;
      float2 cd = ((const float2*)coords)[(size_t)b * 4096 + col];
      float ix = cd.x, iy = cd.y;
      float x0f = floorf(ix), y0f = floorf(iy);
      int x0 = (int)x0f, y0 = (int)y0f;
      float wx1 = ix - x0f, wx0 = 1.f - wx1;
      float wy1 = iy - y0f, wy0 = 1.f - wy1;
      bool vx0 = (unsigned)x0 < 64u, vx1 = (unsigned)(x0 + 1) < 64u;
      bool vy0 = (unsigned)y0 < 64u, vy1 = (unsigned)(y0 + 1) < 64u;
      int x0c = min(max(x0, 0), 63), x1c = min(max(x0 + 1, 0), 63);
      int y0c = min(max(y0, 0), 63), y1c = min(max(y0 + 1, 0), 63);
      float w00 = (vx0 && vy0) ? wx0 * wy0 : 0.f;
      float w10 = (vx1 && vy0) ? wx1 * wy0 : 0.f;
      float w01 = (vx0 && vy1) ? wx0 * wy1 : 0.f;
      float w11 = (vx1 && vy1) ? wx1 * wy1 : 0.f;
      const u16* r00 = gb + ((size_t)(y0c * 64 + x0c)) * 256;
      const u16* r10 = gb + ((size_t)(y0c * 64 + x1c)) * 256;
      const u16* r01 = gb + ((size_t)(y1c * 64 + x0c)) * 256;
      const u16* r11 = gb + ((size_t)(y1c * 64 + x1c)) * 256;
#pragma unroll
      for (int i = 0; i < 4; ++i) {
        int rb = m0 + wr * 64 + i * 16 + kg * 4;
        u16x4 a00 = *(const u16x4*)(r00 + rb);
        u16x4 a10 = *(const u16x4*)(r10 + rb);
        u16x4 a01 = *(const u16x4*)(r01 + rb);
        u16x4 a11 = *(const u16x4*)(r11 + rb);
#pragma unroll
        for (int e = 0; e < 4; ++e) {
          float samp = w00 * bf2f(a00[e]) + w10 * bf2f(a10[e]) +
                       w01 * bf2f(a01[e]) + w11 * bf2f(a11[e]);
          float v = samp + acc[i][j][e];
          Ob[(size_t)(rb + e) * 4096 + col] = v / (1.f + __expf(-v));  // SiLU
        }
      }
    }
  }
}

// ---------------- launch ----------------
extern "C" void kernel_launch(void* const* d_in, const int* in_sizes, int n_in,
                              void* d_out, int out_size, void* d_ws, size_t ws_size,
                              hipStream_t stream) {
  const float* x_local = (const float*)d_in[0];
  const float* x_guide = (const float*)d_in[1];
  const float* w_align = (const float*)d_in[2];
  const float* bn1_g = (const float*)d_in[3];
  const float* bn1_b = (const float*)d_in[4];
  const float* bn1_m = (const float*)d_in[5];
  const float* bn1_v = (const float*)d_in[6];
  const float* w_off1 = (const float*)d_in[7];
  const float* w_off2 = (const float*)d_in[8];
  const float* b_off2 = (const float*)d_in[9];
  const float* w_mlp1 = (const float*)d_in[10];
  const float* bn2_g = (const float*)d_in[11];
  const float* bn2_b = (const float*)d_in[12];
  const float* bn2_m = (const float*)d_in[13];
  const float* bn2_v = (const float*)d_in[14];
  const float* w_mlp2 = (const float*)d_in[15];

  char* ws = (char*)d_ws;
  u16* wa_bf = (u16*)(ws + 0);              // 131072
  u16* w1_bf = (u16*)(ws + 131072);         // 65536
  u16* w2_bf = (u16*)(ws + 196608);         // 65536
  float* bias1 = (float*)(ws + 262144);
  float* bias2 = (float*)(ws + 263168);
  float* coords = (float*)(ws + 263680);    // 524288
  u16* gbuf = (u16*)(ws + 787968);          // 16*4096*256*2 = 33554432 (pixel-major)
  u16* hbuf = (u16*)(ws + 34342400);        // 16*4096*128*2 = 16777216 (pixel-major)
  // sbuf aliases gbuf's region (consumed by coords_kernel before gemm EPI0 writes gbuf)
  float* sbuf = (float*)gbuf;

  prep_weights<<<256, 256, 0, stream>>>(
      w_align, bn1_g, bn1_b, bn1_m, bn1_v,
      w_mlp1, bn2_g, bn2_b, bn2_m, bn2_v, w_mlp2,
      wa_bf, w1_bf, w2_bf, bias1, bias2);

  gconv_kernel<<<dim3(4, 64, 16), 256, 0, stream>>>(x_local, w_off1, sbuf);

  coords_kernel<<<dim3(16, 16), 256, 0, stream>>>(sbuf, w_off2, b_off2, coords);

  // g = BN1(W_align @ x_guide)  -> pixel-major bf16
  gemm_k<256, false, 0><<<dim3(32, 2, 16), 256, 0, stream>>>(
      wa_bf, x_guide, gbuf, bias1, nullptr, nullptr, nullptr);

  // h = GELU(BN2(W1 @ x_local)) -> pixel-major bf16
  gemm_k<256, false, 1><<<dim3(32, 1, 16), 256, 0, stream>>>(
      w1_bf, x_local, hbuf, bias2, nullptr, nullptr, nullptr);

  // out = SiLU(sample(g) + W2 @ h) [f32 channel-major]
  gemm_k<128, true, 2><<<dim3(32, 2, 16), 256, 0, stream>>>(
      w2_bf, hbuf, nullptr, nullptr, gbuf, coords, (float*)d_out);
}

// Round 5
// 132.439 us; speedup vs baseline: 1.0472x; 1.0444x over previous
//
#include <hip/hip_runtime.h>

typedef unsigned short u16;
typedef __bf16 bf16x8 __attribute__((ext_vector_type(8)));
typedef float f32x4 __attribute__((ext_vector_type(4)));
typedef u16 u16x4 __attribute__((ext_vector_type(4)));
typedef u16 u16x8 __attribute__((ext_vector_type(8)));

#define EPS 1e-5f

__device__ __forceinline__ u16 f2bf(float f) {
  unsigned u = __builtin_bit_cast(unsigned, f);
  u += 0x7FFFu + ((u >> 16) & 1u);   // RNE
  return (u16)(u >> 16);
}
__device__ __forceinline__ float bf2f(u16 h) {
  unsigned u = ((unsigned)h) << 16;
  return __builtin_bit_cast(float, u);
}

// ---------------- weight prep: fold BN scale into bf16 weights ----------------
__global__ void prep_weights(
    const float* __restrict__ wa, const float* __restrict__ g1, const float* __restrict__ b1,
    const float* __restrict__ m1, const float* __restrict__ v1,
    const float* __restrict__ w1, const float* __restrict__ g2, const float* __restrict__ b2,
    const float* __restrict__ m2, const float* __restrict__ v2,
    const float* __restrict__ w2,
    u16* __restrict__ wa_o, u16* __restrict__ w1_o, u16* __restrict__ w2_o,
    float* __restrict__ bias1, float* __restrict__ bias2) {
  int t = blockIdx.x * 256 + threadIdx.x;
  if (t < 256 * 256) {
    int m = t >> 8;
    float s = g1[m] / sqrtf(v1[m] + EPS);
    wa_o[t] = f2bf(wa[t] * s);
  }
  if (t < 128 * 256) {
    int m = t >> 8;
    float s = g2[m] / sqrtf(v2[m] + EPS);
    w1_o[t] = f2bf(w1[t] * s);
  }
  if (t < 256 * 128) w2_o[t] = f2bf(w2[t]);
  if (t < 256) bias1[t] = b1[t] - m1[t] * (g1[t] / sqrtf(v1[t] + EPS));
  if (t < 128) bias2[t] = b2[t] - m2[t] * (g2[t] / sqrtf(v2[t] + EPS));
}

// ---------------- grouped 3x3 conv + SiLU -> s[b][q][p] (bf16) ----------------
__global__ __launch_bounds__(256) void gconv_kernel(
    const float* __restrict__ xl, const float* __restrict__ w1,
    u16* __restrict__ sbuf) {
  __shared__ float tile[4][18][66];
  const int tid = threadIdx.x;
  const int band = blockIdx.x;   // 16-row band
  const int q = blockIdx.y;
  const int b = blockIdx.z;
  const float* xb = xl + ((size_t)b * 256 + 4 * q) * 4096;
  for (int i = tid; i < 4 * 18 * 66; i += 256) {
    int ci = i / (18 * 66);
    int rem = i - ci * (18 * 66);
    int r = rem / 66, c = rem - r * 66;
    int gy = band * 16 - 1 + r, gx = c - 1;
    float v = 0.f;
    if ((unsigned)gy < 64u && (unsigned)gx < 64u)
      v = xb[(size_t)ci * 4096 + gy * 64 + gx];
    tile[ci][r][c] = v;
  }
  float wq[36];
#pragma unroll
  for (int i = 0; i < 36; ++i) wq[i] = w1[q * 36 + i];
  __syncthreads();
  const int c = tid & 63, r0 = tid >> 6;
  u16* sp = sbuf + ((size_t)(b * 64 + q)) * 4096 + band * 1024;
#pragma unroll
  for (int k = 0; k < 4; ++k) {
    int r = r0 * 4 + k;
    float s = 0.f;
#pragma unroll
    for (int ci = 0; ci < 4; ++ci)
#pragma unroll
      for (int dy = 0; dy < 3; ++dy)
#pragma unroll
        for (int dx = 0; dx < 3; ++dx)
          s += wq[ci * 9 + dy * 3 + dx] * tile[ci][r + dy][c + dx];
    sp[r * 64 + c] = f2bf(s / (1.f + __expf(-s)));  // SiLU
  }
}

// ---------------- 1x1 conv over groups -> sample coords ----------------
__global__ __launch_bounds__(256) void coords_kernel(
    const u16* __restrict__ sbuf, const float* __restrict__ w2,
    const float* __restrict__ b2, float* __restrict__ coords) {
  __shared__ float sw2[128];
  const int tid = threadIdx.x;
  if (tid < 128) sw2[tid] = w2[tid];
  __syncthreads();
  const int b = blockIdx.y;
  const int p = blockIdx.x * 256 + tid;
  const u16* sp = sbuf + (size_t)b * 64 * 4096 + p;
  float ax = 0.f, ay = 0.f;
#pragma unroll 8
  for (int q = 0; q < 64; ++q) {
    float v = bf2f(sp[(size_t)q * 4096]);
    ax += sw2[q] * v;
    ay += sw2[64 + q] * v;
  }
  int y = p >> 6, x = p & 63;
  float ix = (64.f / 63.f) * (float)x + ax + b2[0] - 0.5f;
  float iy = (64.f / 63.f) * (float)y + ay + b2[1] - 0.5f;
  ((float2*)coords)[(size_t)b * 4096 + p] = make_float2(ix, iy);
}

// ---------------- templated MFMA GEMM ----------------
// BM=BN=128, BK=32, 4 waves, wave = 64x64 quadrant (4x4 frags of 16x16x32).
// EPI 0: +bias -> g[p][256] bf16. EPI 1: +bias, GELU -> h[p][128] bf16.
// EPI 2: pre-gathered bilinear sample (LDS) + acc, SiLU -> out f32 [c][p].
template <int K, bool B_PIXMAJOR_BF16, int EPI>
__global__ __launch_bounds__(256, 2) void gemm_k(
    const u16* __restrict__ A, const void* __restrict__ Bsrc,
    u16* __restrict__ OutBf, const float* __restrict__ bias,
    const u16* __restrict__ g, const float* __restrict__ coords,
    float* __restrict__ out_f) {
  __shared__ u16 Al[128][40];  // 32 data + 8 pad (row = 80B)
  __shared__ u16 Bl[128][40];  // [n][k]
  __shared__ u16 Samp[(EPI == 2) ? 128 * 128 : 1];  // sampled g tile, XOR-swizzled
  const int tid = threadIdx.x;
  const int b = blockIdx.z;
  const int n0 = blockIdx.x * 128;
  const int m0 = blockIdx.y * 128;
  const int wave = tid >> 6, lane = tid & 63;
  const int wr = wave >> 1, wc = wave & 1;
  const int lr = lane & 15, kg = lane >> 4;

  // ---- EPI2 pre-gather: coalesced bilinear sample of g -> LDS ----
  if constexpr (EPI == 2) {
    const u16* gb = g + (size_t)b * 4096 * 256 + m0;  // this block's channel half
    const int half = lane >> 5;   // which pixel of the pair
    const int c4 = lane & 31;     // channel quad within 128
    for (int it = 0; it < 16; ++it) {
      int pl = wave * 32 + it * 2 + half;   // local pixel 0..127
      float2 cd = ((const float2*)coords)[(size_t)b * 4096 + n0 + pl];
      float ix = cd.x, iy = cd.y;
      float x0f = floorf(ix), y0f = floorf(iy);
      int x0 = (int)x0f, y0 = (int)y0f;
      float wx1 = ix - x0f, wx0 = 1.f - wx1;
      float wy1 = iy - y0f, wy0 = 1.f - wy1;
      bool vx0 = (unsigned)x0 < 64u, vx1 = (unsigned)(x0 + 1) < 64u;
      bool vy0 = (unsigned)y0 < 64u, vy1 = (unsigned)(y0 + 1) < 64u;
      int x0c = min(max(x0, 0), 63), x1c = min(max(x0 + 1, 0), 63);
      int y0c = min(max(y0, 0), 63), y1c = min(max(y0 + 1, 0), 63);
      float w00 = (vx0 && vy0) ? wx0 * wy0 : 0.f;
      float w10 = (vx1 && vy0) ? wx1 * wy0 : 0.f;
      float w01 = (vx0 && vy1) ? wx0 * wy1 : 0.f;
      float w11 = (vx1 && vy1) ? wx1 * wy1 : 0.f;
      // 32 lanes x 8B = 256B contiguous per neighbor row (4 lines/instr)
      u16x4 a00 = *(const u16x4*)(gb + (size_t)(y0c * 64 + x0c) * 256 + c4 * 4);
      u16x4 a10 = *(const u16x4*)(gb + (size_t)(y0c * 64 + x1c) * 256 + c4 * 4);
      u16x4 a01 = *(const u16x4*)(gb + (size_t)(y1c * 64 + x0c) * 256 + c4 * 4);
      u16x4 a11 = *(const u16x4*)(gb + (size_t)(y1c * 64 + x1c) * 256 + c4 * 4);
      u16x4 o;
#pragma unroll
      for (int e = 0; e < 4; ++e) {
        float v = w00 * bf2f(a00[e]) + w10 * bf2f(a10[e]) +
                  w01 * bf2f(a01[e]) + w11 * bf2f(a11[e]);
        o[e] = f2bf(v);
      }
      int byt = (c4 * 8) ^ ((pl & 7) << 4);  // XOR swizzle, 8B-aligned
      *(u16x4*)((char*)Samp + pl * 256 + byt) = o;
    }
  }

  f32x4 acc[4][4] = {};

  const float* Bf = (const float*)Bsrc + (size_t)b * K * 4096;
  const u16* Bh = (const u16*)Bsrc + (size_t)b * 4096 * K;  // pixel-major

  for (int kt = 0; kt < K / 32; ++kt) {
    // ---- stage A ----
#pragma unroll
    for (int c = 0; c < 2; ++c) {
      int ch = tid + c * 256;
      int m = ch >> 2, pos = (ch & 3) * 8;
      u16x8 v = *(const u16x8*)(A + (size_t)(m0 + m) * K + kt * 32 + pos);
      *(u16x8*)&Al[m][pos] = v;
    }
    // ---- stage B ----
    if (B_PIXMAJOR_BF16) {
#pragma unroll
      for (int c = 0; c < 2; ++c) {
        int idx = tid + c * 256;
        int pl = idx >> 2, kq = idx & 3;
        u16x8 v = *(const u16x8*)(Bh + (size_t)(n0 + pl) * K + kt * 32 + kq * 8);
        *(u16x8*)&Bl[pl][kq * 8] = v;
      }
    } else {
      int nq = tid & 31, kq = tid >> 5;
      int kb = kt * 32 + kq * 4;
      int nb = n0 + nq * 4;
      f32x4 r[4];
#pragma unroll
      for (int i = 0; i < 4; ++i)
        r[i] = *(const f32x4*)(Bf + (size_t)(kb + i) * 4096 + nb);
#pragma unroll
      for (int j = 0; j < 4; ++j) {
        u16x4 w = {f2bf(r[0][j]), f2bf(r[1][j]), f2bf(r[2][j]), f2bf(r[3][j])};
        *(u16x4*)&Bl[nq * 4 + j][kq * 4] = w;
      }
    }
    __syncthreads();
    bf16x8 af[4], bfr[4];
#pragma unroll
    for (int i = 0; i < 4; ++i) {
      af[i] = *(const bf16x8*)&Al[wr * 64 + i * 16 + lr][kg * 8];
      bfr[i] = *(const bf16x8*)&Bl[wc * 64 + i * 16 + lr][kg * 8];
    }
#pragma unroll
    for (int i = 0; i < 4; ++i)
#pragma unroll
      for (int j = 0; j < 4; ++j)
        acc[i][j] = __builtin_amdgcn_mfma_f32_16x16x32_bf16(af[i], bfr[j], acc[i][j], 0, 0, 0);
    __syncthreads();
  }

  // ---- epilogue ----
  if constexpr (EPI == 0 || EPI == 1) {
    const int CT = (EPI == 0) ? 256 : 128;
    u16* O = OutBf + (size_t)b * 4096 * CT;
#pragma unroll
    for (int i = 0; i < 4; ++i) {
      int rb = m0 + wr * 64 + i * 16 + kg * 4;
      f32x4 b4 = *(const f32x4*)(bias + rb);
#pragma unroll
      for (int j = 0; j < 4; ++j) {
        int col = n0 + wc * 64 + j * 16 + lr;
        u16x4 w;
#pragma unroll
        for (int e = 0; e < 4; ++e) {
          float v = acc[i][j][e] + b4[e];
          if (EPI == 1) v = 0.5f * v * (1.f + erff(v * 0.70710678118f));  // exact GELU
          w[e] = f2bf(v);
        }
        *(u16x4*)(O + (size_t)col * CT + rb) = w;
      }
    }
  } else {
    float* Ob = out_f + (size_t)b * 256 * 4096;
#pragma unroll
    for (int j = 0; j < 4; ++j) {
      int col_l = wc * 64 + j * 16 + lr;
      int col = n0 + col_l;
#pragma unroll
      for (int i = 0; i < 4; ++i) {
        int ch_l = wr * 64 + i * 16 + kg * 4;
        int byt = (ch_l * 2) ^ ((col_l & 7) << 4);
        u16x4 s4 = *(const u16x4*)((const char*)Samp + col_l * 256 + byt);
#pragma unroll
        for (int e = 0; e < 4; ++e) {
          float v = bf2f(s4[e]) + acc[i][j][e];
          Ob[(size_t)(m0 + ch_l + e) * 4096 + col] = v / (1.f + __expf(-v));  // SiLU
        }
      }
    }
  }
}

// ---------------- launch ----------------
extern "C" void kernel_launch(void* const* d_in, const int* in_sizes, int n_in,
                              void* d_out, int out_size, void* d_ws, size_t ws_size,
                              hipStream_t stream) {
  const float* x_local = (const float*)d_in[0];
  const float* x_guide = (const float*)d_in[1];
  const float* w_align = (const float*)d_in[2];
  const float* bn1_g = (const float*)d_in[3];
  const float* bn1_b = (const float*)d_in[4];
  const float* bn1_m = (const float*)d_in[5];
  const float* bn1_v = (const float*)d_in[6];
  const float* w_off1 = (const float*)d_in[7];
  const float* w_off2 = (const float*)d_in[8];
  const float* b_off2 = (const float*)d_in[9];
  const float* w_mlp1 = (const float*)d_in[10];
  const float* bn2_g = (const float*)d_in[11];
  const float* bn2_b = (const float*)d_in[12];
  const float* bn2_m = (const float*)d_in[13];
  const float* bn2_v = (const float*)d_in[14];
  const float* w_mlp2 = (const float*)d_in[15];

  char* ws = (char*)d_ws;
  u16* wa_bf = (u16*)(ws + 0);              // 131072
  u16* w1_bf = (u16*)(ws + 131072);         // 65536
  u16* w2_bf = (u16*)(ws + 196608);         // 65536
  float* bias1 = (float*)(ws + 262144);
  float* bias2 = (float*)(ws + 263168);
  float* coords = (float*)(ws + 263680);    // 524288
  u16* gbuf = (u16*)(ws + 787968);          // 16*4096*256*2 = 33554432 (pixel-major)
  u16* hbuf = (u16*)(ws + 34342400);        // 16*4096*128*2 = 16777216 (pixel-major)
  // sbuf (bf16, 8.4 MB) aliases gbuf region (consumed before gbuf written)
  u16* sbuf = gbuf;

  prep_weights<<<256, 256, 0, stream>>>(
      w_align, bn1_g, bn1_b, bn1_m, bn1_v,
      w_mlp1, bn2_g, bn2_b, bn2_m, bn2_v, w_mlp2,
      wa_bf, w1_bf, w2_bf, bias1, bias2);

  gconv_kernel<<<dim3(4, 64, 16), 256, 0, stream>>>(x_local, w_off1, sbuf);

  coords_kernel<<<dim3(16, 16), 256, 0, stream>>>(sbuf, w_off2, b_off2, coords);

  // g = BN1(W_align @ x_guide)  -> pixel-major bf16
  gemm_k<256, false, 0><<<dim3(32, 2, 16), 256, 0, stream>>>(
      wa_bf, x_guide, gbuf, bias1, nullptr, nullptr, nullptr);

  // h = GELU(BN2(W1 @ x_local)) -> pixel-major bf16
  gemm_k<256, false, 1><<<dim3(32, 1, 16), 256, 0, stream>>>(
      w1_bf, x_local, hbuf, bias2, nullptr, nullptr, nullptr);

  // out = SiLU(sample(g) + W2 @ h) [f32 channel-major]
  gemm_k<128, true, 2><<<dim3(32, 2, 16), 256, 0, stream>>>(
      w2_bf, hbuf, nullptr, nullptr, gbuf, coords, (float*)d_out);
}

// Round 6
// 131.996 us; speedup vs baseline: 1.0508x; 1.0034x over previous
//
#include <hip/hip_runtime.h>

typedef unsigned short u16;
typedef __bf16 bf16x8 __attribute__((ext_vector_type(8)));
typedef float f32x4 __attribute__((ext_vector_type(4)));
typedef u16 u16x2 __attribute__((ext_vector_type(2)));
typedef u16 u16x4 __attribute__((ext_vector_type(4)));
typedef u16 u16x8 __attribute__((ext_vector_type(8)));

#define EPS 1e-5f

__device__ __forceinline__ u16 f2bf(float f) {
  unsigned u = __builtin_bit_cast(unsigned, f);
  u += 0x7FFFu + ((u >> 16) & 1u);   // RNE
  return (u16)(u >> 16);
}
__device__ __forceinline__ float bf2f(u16 h) {
  unsigned u = ((unsigned)h) << 16;
  return __builtin_bit_cast(float, u);
}

// ---------------- weight prep ----------------
// Acat[c][384] = [ wa*s1 (k<256) | w2 (k>=256) ]; w1_o = w1*s2; biases.
// grid 256 blocks x 384 threads
__global__ void prep_weights(
    const float* __restrict__ wa, const float* __restrict__ g1, const float* __restrict__ b1,
    const float* __restrict__ m1, const float* __restrict__ v1,
    const float* __restrict__ w1, const float* __restrict__ g2, const float* __restrict__ b2,
    const float* __restrict__ m2, const float* __restrict__ v2,
    const float* __restrict__ w2,
    u16* __restrict__ Acat, u16* __restrict__ w1_o,
    float* __restrict__ bias1, float* __restrict__ bias2) {
  int c = blockIdx.x, k = threadIdx.x;
  float s1 = g1[c] / sqrtf(v1[c] + EPS);
  if (k < 256) Acat[c * 384 + k] = f2bf(wa[c * 256 + k] * s1);
  else         Acat[c * 384 + k] = f2bf(w2[c * 128 + (k - 256)]);
  if (c < 128) {
    float s2 = g2[c] / sqrtf(v2[c] + EPS);
    if (k < 256) w1_o[c * 256 + k] = f2bf(w1[c * 256 + k] * s2);
    if (k == 256) bias2[c] = b2[c] - m2[c] * s2;
  }
  if (k == 0) bias1[c] = b1[c] - m1[c] * s1;
}

// ---------------- grouped 3x3 conv + SiLU -> s[b][q][p] (bf16) ----------------
__global__ __launch_bounds__(256) void gconv_kernel(
    const float* __restrict__ xl, const float* __restrict__ w1,
    u16* __restrict__ sbuf) {
  __shared__ float tile[4][18][66];
  const int tid = threadIdx.x;
  const int band = blockIdx.x;   // 16-row band
  const int q = blockIdx.y;
  const int b = blockIdx.z;
  const float* xb = xl + ((size_t)b * 256 + 4 * q) * 4096;
  for (int i = tid; i < 4 * 18 * 66; i += 256) {
    int ci = i / (18 * 66);
    int rem = i - ci * (18 * 66);
    int r = rem / 66, c = rem - r * 66;
    int gy = band * 16 - 1 + r, gx = c - 1;
    float v = 0.f;
    if ((unsigned)gy < 64u && (unsigned)gx < 64u)
      v = xb[(size_t)ci * 4096 + gy * 64 + gx];
    tile[ci][r][c] = v;
  }
  float wq[36];
#pragma unroll
  for (int i = 0; i < 36; ++i) wq[i] = w1[q * 36 + i];
  __syncthreads();
  const int c = tid & 63, r0 = tid >> 6;
  u16* sp = sbuf + ((size_t)(b * 64 + q)) * 4096 + band * 1024;
#pragma unroll
  for (int k = 0; k < 4; ++k) {
    int r = r0 * 4 + k;
    float s = 0.f;
#pragma unroll
    for (int ci = 0; ci < 4; ++ci)
#pragma unroll
      for (int dy = 0; dy < 3; ++dy)
#pragma unroll
        for (int dx = 0; dx < 3; ++dx)
          s += wq[ci * 9 + dy * 3 + dx] * tile[ci][r + dy][c + dx];
    sp[r * 64 + c] = f2bf(s / (1.f + __expf(-s)));  // SiLU
  }
}

// ---------------- coords + bilinear-sample x_guide -> xgs[b][k][p], wsum ----------------
// block = one image row (64 px), 256 thr = 4 k-lanes x 64 px. grid 1024 (XCD-chunked).
__global__ __launch_bounds__(256) void sampler_kernel(
    const u16* __restrict__ sbuf, const float* __restrict__ w2,
    const float* __restrict__ b2, const float* __restrict__ xg,
    u16* __restrict__ xgs, float* __restrict__ wsum) {
  __shared__ float sw2[128];
  __shared__ float part[2][4][64];
  const int wg = blockIdx.x;
  const int idx = (wg & 7) * 128 + (wg >> 3);  // XCD-chunked: consecutive rows same XCD
  const int b = idx >> 6, row = idx & 63;
  const int tid = threadIdx.x, px = tid & 63, ko = tid >> 6;
  if (tid < 128) sw2[tid] = w2[tid];
  __syncthreads();
  // ---- offset = 1x1 conv over 64 groups (split across ko) ----
  const u16* sp = sbuf + (size_t)b * 64 * 4096 + row * 64 + px;
  float ax = 0.f, ay = 0.f;
#pragma unroll
  for (int qq = 0; qq < 16; ++qq) {
    int q = ko * 16 + qq;
    float v = bf2f(sp[(size_t)q * 4096]);
    ax += sw2[q] * v;
    ay += sw2[64 + q] * v;
  }
  part[0][ko][px] = ax;
  part[1][ko][px] = ay;
  __syncthreads();
  float ox = part[0][0][px] + part[0][1][px] + part[0][2][px] + part[0][3][px] + b2[0];
  float oy = part[1][0][px] + part[1][1][px] + part[1][2][px] + part[1][3][px] + b2[1];
  // ix = 64x/63 + off - 0.5  (align_corners=False)
  float ix = (64.f / 63.f) * (float)px + ox - 0.5f;
  float iy = (64.f / 63.f) * (float)row + oy - 0.5f;
  float x0f = floorf(ix), y0f = floorf(iy);
  int x0 = (int)x0f, y0 = (int)y0f;
  float wx1 = ix - x0f, wx0 = 1.f - wx1;
  float wy1 = iy - y0f, wy0 = 1.f - wy1;
  bool vx0 = (unsigned)x0 < 64u, vx1 = (unsigned)(x0 + 1) < 64u;
  bool vy0 = (unsigned)y0 < 64u, vy1 = (unsigned)(y0 + 1) < 64u;
  int x0c = min(max(x0, 0), 63), x1c = min(max(x0 + 1, 0), 63);
  int y0c = min(max(y0, 0), 63), y1c = min(max(y0 + 1, 0), 63);
  float w00 = (vx0 && vy0) ? wx0 * wy0 : 0.f;
  float w10 = (vx1 && vy0) ? wx1 * wy0 : 0.f;
  float w01 = (vx0 && vy1) ? wx0 * wy1 : 0.f;
  float w11 = (vx1 && vy1) ? wx1 * wy1 : 0.f;
  const int p = row * 64 + px;
  if (ko == 0) wsum[(size_t)b * 4096 + p] = w00 + w10 + w01 + w11;
  const int i00 = y0c * 64 + x0c, i10 = y0c * 64 + x1c;
  const int i01 = y1c * 64 + x0c, i11 = y1c * 64 + x1c;
  const float* xb = xg + (size_t)b * 256 * 4096;
  u16* xo = xgs + (size_t)b * 256 * 4096 + p;
  // sample(x_guide) for all 256 channels (4-way k-parallel, px-coalesced)
#pragma unroll 4
  for (int k = ko; k < 256; k += 4) {
    const float* bb = xb + (size_t)k * 4096;
    float v = w00 * bb[i00] + w10 * bb[i10] + w01 * bb[i01] + w11 * bb[i11];
    xo[(size_t)k * 4096] = f2bf(v);
  }
}

// ---------------- h GEMM: h = GELU(BN2(W1 @ x_local)) -> pixel-major bf16 ----------------
// M=128, K=256, BN=128, 4 waves; B = x_local f32 channel-major (reg transpose).
__global__ __launch_bounds__(256, 2) void gemm_h(
    const u16* __restrict__ A, const float* __restrict__ Bsrc,
    u16* __restrict__ Out, const float* __restrict__ bias) {
  __shared__ u16 Al[128][40];
  __shared__ u16 Bl[128][40];
  const int tid = threadIdx.x;
  const int b = blockIdx.y;
  const int n0 = blockIdx.x * 128;
  const int wave = tid >> 6, lane = tid & 63;
  const int wr = wave >> 1, wc = wave & 1;
  const int lr = lane & 15, kg = lane >> 4;
  f32x4 acc[4][4] = {};
  const float* Bf = Bsrc + (size_t)b * 256 * 4096;

  for (int kt = 0; kt < 8; ++kt) {
    // stage A: 128x32
    {
      int m = tid >> 1, pos = (tid & 1) * 16;
      u16x8 v0 = *(const u16x8*)(A + (size_t)m * 256 + kt * 32 + pos);
      u16x8 v1 = *(const u16x8*)(A + (size_t)m * 256 + kt * 32 + pos + 8);
      *(u16x8*)&Al[m][pos] = v0;
      *(u16x8*)&Al[m][pos + 8] = v1;
    }
    // stage B: f32 [K][4096] -> bf16 [n][k], 4x4 micro transpose
    {
      int nq = tid & 31, kq = tid >> 5;
      int kb = kt * 32 + kq * 4;
      int nb = n0 + nq * 4;
      f32x4 r[4];
#pragma unroll
      for (int i = 0; i < 4; ++i)
        r[i] = *(const f32x4*)(Bf + (size_t)(kb + i) * 4096 + nb);
#pragma unroll
      for (int j = 0; j < 4; ++j) {
        u16x4 w = {f2bf(r[0][j]), f2bf(r[1][j]), f2bf(r[2][j]), f2bf(r[3][j])};
        *(u16x4*)&Bl[nq * 4 + j][kq * 4] = w;
      }
    }
    __syncthreads();
    bf16x8 af[4], bfr[4];
#pragma unroll
    for (int i = 0; i < 4; ++i) {
      af[i] = *(const bf16x8*)&Al[wr * 64 + i * 16 + lr][kg * 8];
      bfr[i] = *(const bf16x8*)&Bl[wc * 64 + i * 16 + lr][kg * 8];
    }
#pragma unroll
    for (int i = 0; i < 4; ++i)
#pragma unroll
      for (int j = 0; j < 4; ++j)
        acc[i][j] = __builtin_amdgcn_mfma_f32_16x16x32_bf16(af[i], bfr[j], acc[i][j], 0, 0, 0);
    __syncthreads();
  }
  u16* O = Out + (size_t)b * 4096 * 128;
#pragma unroll
  for (int i = 0; i < 4; ++i) {
    int rb = wr * 64 + i * 16 + kg * 4;
    f32x4 b4 = *(const f32x4*)(bias + rb);
#pragma unroll
    for (int j = 0; j < 4; ++j) {
      int col = n0 + wc * 64 + j * 16 + lr;
      u16x4 w;
#pragma unroll
      for (int e = 0; e < 4; ++e) {
        float v = acc[i][j][e] + b4[e];
        v = 0.5f * v * (1.f + erff(v * 0.70710678118f));  // exact GELU
        w[e] = f2bf(v);
      }
      *(u16x4*)(O + (size_t)col * 128 + rb) = w;  // pixel-major
    }
  }
}

// ---------------- final fused GEMM: out = SiLU(Acat @ [xgs; h] + bias1*wsum) ----------------
// M=256, K=384 (256 xgs + 128 h), BN=128, 512 thr = 8 waves (4 ch-quads x 2 px-halves).
__global__ __launch_bounds__(512, 2) void gemm_final(
    const u16* __restrict__ A,    // [256][384] bf16
    const u16* __restrict__ xgs,  // [b][256][4096] channel-major bf16
    const u16* __restrict__ hb,   // [b][4096][128] pixel-major bf16
    const float* __restrict__ bias1, const float* __restrict__ wsum,
    float* __restrict__ out) {
  __shared__ u16 Al[256][40];
  __shared__ u16 Bl[128][40];
  const int tid = threadIdx.x;
  const int b = blockIdx.y;
  const int n0 = blockIdx.x * 128;
  const int wave = tid >> 6, lane = tid & 63;
  const int wr = wave >> 1, wc = wave & 1;   // wr: 64-ch quad, wc: 64-px half
  const int lr = lane & 15, kg = lane >> 4;
  f32x4 acc[4][4] = {};
  const u16* xb = xgs + (size_t)b * 256 * 4096;
  const u16* hp = hb + (size_t)b * 4096 * 128;

  for (int kt = 0; kt < 12; ++kt) {
    // ---- stage A: 256 rows x 32 k ----
#pragma unroll
    for (int c = 0; c < 2; ++c) {
      int ch = tid + c * 512;
      int m = ch >> 2, pos = (ch & 3) * 8;
      *(u16x8*)&Al[m][pos] = *(const u16x8*)(A + (size_t)m * 384 + kt * 32 + pos);
    }
    // ---- stage B ----
    if (kt < 8) {
      // xgs channel-major: 2k x 4px micro transpose
      int kq2 = tid >> 5;  // 0..15
      int nq = tid & 31;
      int k0 = kt * 32 + kq2 * 2;
      u16x4 r0 = *(const u16x4*)(xb + (size_t)k0 * 4096 + n0 + nq * 4);
      u16x4 r1 = *(const u16x4*)(xb + (size_t)(k0 + 1) * 4096 + n0 + nq * 4);
#pragma unroll
      for (int j = 0; j < 4; ++j) {
        u16x2 w = {r0[j], r1[j]};
        *(u16x2*)&Bl[nq * 4 + j][kq2 * 2] = w;
      }
    } else {
      // h pixel-major: straight vector copy
      int pl = tid >> 2, kq = tid & 3;
      *(u16x8*)&Bl[pl][kq * 8] =
          *(const u16x8*)(hp + (size_t)(n0 + pl) * 128 + (kt - 8) * 32 + kq * 8);
    }
    __syncthreads();
    bf16x8 af[4], bfr[4];
#pragma unroll
    for (int i = 0; i < 4; ++i) {
      af[i] = *(const bf16x8*)&Al[wr * 64 + i * 16 + lr][kg * 8];
      bfr[i] = *(const bf16x8*)&Bl[wc * 64 + i * 16 + lr][kg * 8];
    }
#pragma unroll
    for (int i = 0; i < 4; ++i)
#pragma unroll
      for (int j = 0; j < 4; ++j)
        acc[i][j] = __builtin_amdgcn_mfma_f32_16x16x32_bf16(af[i], bfr[j], acc[i][j], 0, 0, 0);
    __syncthreads();
  }

  float* Ob = out + (size_t)b * 256 * 4096;
#pragma unroll
  for (int j = 0; j < 4; ++j) {
    int col = n0 + wc * 64 + j * 16 + lr;
    float ws = wsum[(size_t)b * 4096 + col];
#pragma unroll
    for (int i = 0; i < 4; ++i) {
      int rb = wr * 64 + i * 16 + kg * 4;
      f32x4 b4 = *(const f32x4*)(bias1 + rb);
#pragma unroll
      for (int e = 0; e < 4; ++e) {
        float v = acc[i][j][e] + b4[e] * ws;  // sampled bias (zeros padding)
        Ob[(size_t)(rb + e) * 4096 + col] = v / (1.f + __expf(-v));  // SiLU
      }
    }
  }
}

// ---------------- launch ----------------
extern "C" void kernel_launch(void* const* d_in, const int* in_sizes, int n_in,
                              void* d_out, int out_size, void* d_ws, size_t ws_size,
                              hipStream_t stream) {
  const float* x_local = (const float*)d_in[0];
  const float* x_guide = (const float*)d_in[1];
  const float* w_align = (const float*)d_in[2];
  const float* bn1_g = (const float*)d_in[3];
  const float* bn1_b = (const float*)d_in[4];
  const float* bn1_m = (const float*)d_in[5];
  const float* bn1_v = (const float*)d_in[6];
  const float* w_off1 = (const float*)d_in[7];
  const float* w_off2 = (const float*)d_in[8];
  const float* b_off2 = (const float*)d_in[9];
  const float* w_mlp1 = (const float*)d_in[10];
  const float* bn2_g = (const float*)d_in[11];
  const float* bn2_b = (const float*)d_in[12];
  const float* bn2_m = (const float*)d_in[13];
  const float* bn2_v = (const float*)d_in[14];
  const float* w_mlp2 = (const float*)d_in[15];

  char* ws = (char*)d_ws;
  u16* Acat = (u16*)(ws + 0);               // 256*384*2 = 196608
  u16* w1_bf = (u16*)(ws + 196608);         // 128*256*2 = 65536 -> 262144
  float* bias1 = (float*)(ws + 262144);     // 1024      -> 263168
  float* bias2 = (float*)(ws + 263168);     // 512       -> 263680
  float* wsum = (float*)(ws + 263680);      // 16*4096*4 = 262144 -> 525824
  u16* xgs = (u16*)(ws + 525824);           // 16*256*4096*2 = 33554432 -> 34080256
  u16* hbuf = (u16*)(ws + 34080256);        // 16*4096*128*2 = 16777216 -> 50857472
  // sbuf (8.4 MB bf16) aliases hbuf: written by gconv, consumed by sampler,
  // then hbuf is written by gemm_h (stream-ordered, no overlap in liveness).
  u16* sbuf = hbuf;

  prep_weights<<<256, 384, 0, stream>>>(
      w_align, bn1_g, bn1_b, bn1_m, bn1_v,
      w_mlp1, bn2_g, bn2_b, bn2_m, bn2_v, w_mlp2,
      Acat, w1_bf, bias1, bias2);

  gconv_kernel<<<dim3(4, 64, 16), 256, 0, stream>>>(x_local, w_off1, sbuf);

  sampler_kernel<<<1024, 256, 0, stream>>>(sbuf, w_off2, b_off2, x_guide, xgs, wsum);

  gemm_h<<<dim3(32, 16), 256, 0, stream>>>(w1_bf, x_local, hbuf, bias2);

  gemm_final<<<dim3(32, 16), 512, 0, stream>>>(Acat, xgs, hbuf, bias1, wsum, (float*)d_out);
}

// Round 7
// 130.338 us; speedup vs baseline: 1.0641x; 1.0127x over previous
//
#include <hip/hip_runtime.h>

typedef unsigned short u16;
typedef __bf16 bf16x8 __attribute__((ext_vector_type(8)));
typedef float f32x4 __attribute__((ext_vector_type(4)));
typedef u16 u16x2 __attribute__((ext_vector_type(2)));
typedef u16 u16x4 __attribute__((ext_vector_type(4)));
typedef u16 u16x8 __attribute__((ext_vector_type(8)));

#define EPS 1e-5f

__device__ __forceinline__ u16 f2bf(float f) {
  unsigned u = __builtin_bit_cast(unsigned, f);
  u += 0x7FFFu + ((u >> 16) & 1u);   // RNE
  return (u16)(u >> 16);
}
__device__ __forceinline__ float bf2f(u16 h) {
  unsigned u = ((unsigned)h) << 16;
  return __builtin_bit_cast(float, u);
}

// ---------------- weight prep ----------------
__global__ void prep_weights(
    const float* __restrict__ wa, const float* __restrict__ g1, const float* __restrict__ b1,
    const float* __restrict__ m1, const float* __restrict__ v1,
    const float* __restrict__ w1, const float* __restrict__ g2, const float* __restrict__ b2,
    const float* __restrict__ m2, const float* __restrict__ v2,
    const float* __restrict__ w2,
    u16* __restrict__ Acat, u16* __restrict__ w1_o,
    float* __restrict__ bias1, float* __restrict__ bias2) {
  int c = blockIdx.x, k = threadIdx.x;
  float s1 = g1[c] / sqrtf(v1[c] + EPS);
  if (k < 256) Acat[c * 384 + k] = f2bf(wa[c * 256 + k] * s1);
  else         Acat[c * 384 + k] = f2bf(w2[c * 128 + (k - 256)]);
  if (c < 128) {
    float s2 = g2[c] / sqrtf(v2[c] + EPS);
    if (k < 256) w1_o[c * 256 + k] = f2bf(w1[c * 256 + k] * s2);
    if (k == 256) bias2[c] = b2[c] - m2[c] * s2;
  }
  if (k == 0) bias1[c] = b1[c] - m1[c] * s1;
}

// ---------------- grouped 3x3 conv + SiLU -> s[b][q][p] (bf16) ----------------
__global__ __launch_bounds__(256) void gconv_kernel(
    const float* __restrict__ xl, const float* __restrict__ w1,
    u16* __restrict__ sbuf) {
  __shared__ float tile[4][18][66];
  const int tid = threadIdx.x;
  const int band = blockIdx.x;   // 16-row band
  const int q = blockIdx.y;
  const int b = blockIdx.z;
  const float* xb = xl + ((size_t)b * 256 + 4 * q) * 4096;
  for (int i = tid; i < 4 * 18 * 66; i += 256) {
    int ci = i / (18 * 66);
    int rem = i - ci * (18 * 66);
    int r = rem / 66, c = rem - r * 66;
    int gy = band * 16 - 1 + r, gx = c - 1;
    float v = 0.f;
    if ((unsigned)gy < 64u && (unsigned)gx < 64u)
      v = xb[(size_t)ci * 4096 + gy * 64 + gx];
    tile[ci][r][c] = v;
  }
  float wq[36];
#pragma unroll
  for (int i = 0; i < 36; ++i) wq[i] = w1[q * 36 + i];
  __syncthreads();
  const int c = tid & 63, r0 = tid >> 6;
  u16* sp = sbuf + ((size_t)(b * 64 + q)) * 4096 + band * 1024;
#pragma unroll
  for (int k = 0; k < 4; ++k) {
    int r = r0 * 4 + k;
    float s = 0.f;
#pragma unroll
    for (int ci = 0; ci < 4; ++ci)
#pragma unroll
      for (int dy = 0; dy < 3; ++dy)
#pragma unroll
        for (int dx = 0; dx < 3; ++dx)
          s += wq[ci * 9 + dy * 3 + dx] * tile[ci][r + dy][c + dx];
    sp[r * 64 + c] = f2bf(s / (1.f + __expf(-s)));  // SiLU
  }
}

// ---------------- 1x1 conv over groups -> coords (float2) + wsum ----------------
__global__ __launch_bounds__(256) void coords_kernel(
    const u16* __restrict__ sbuf, const float* __restrict__ w2,
    const float* __restrict__ b2, float* __restrict__ coords,
    float* __restrict__ wsum) {
  __shared__ float sw2[128];
  const int tid = threadIdx.x;
  if (tid < 128) sw2[tid] = w2[tid];
  __syncthreads();
  const int b = blockIdx.y;
  const int p = blockIdx.x * 256 + tid;
  const u16* sp = sbuf + (size_t)b * 64 * 4096 + p;
  float ax = 0.f, ay = 0.f;
#pragma unroll 8
  for (int q = 0; q < 64; ++q) {
    float v = bf2f(sp[(size_t)q * 4096]);
    ax += sw2[q] * v;
    ay += sw2[64 + q] * v;
  }
  int y = p >> 6, x = p & 63;
  float ix = (64.f / 63.f) * (float)x + ax + b2[0] - 0.5f;
  float iy = (64.f / 63.f) * (float)y + ay + b2[1] - 0.5f;
  ((float2*)coords)[(size_t)b * 4096 + p] = make_float2(ix, iy);
  // wsum for sampled-bias correction (zeros padding)
  float x0f = floorf(ix), y0f = floorf(iy);
  int x0 = (int)x0f, y0 = (int)y0f;
  float wx1 = ix - x0f, wx0 = 1.f - wx1;
  float wy1 = iy - y0f, wy0 = 1.f - wy1;
  bool vx0 = (unsigned)x0 < 64u, vx1 = (unsigned)(x0 + 1) < 64u;
  bool vy0 = (unsigned)y0 < 64u, vy1 = (unsigned)(y0 + 1) < 64u;
  float s = (vx0 && vy0 ? wx0 * wy0 : 0.f) + (vx1 && vy0 ? wx1 * wy0 : 0.f) +
            (vx0 && vy1 ? wx0 * wy1 : 0.f) + (vx1 && vy1 ? wx1 * wy1 : 0.f);
  wsum[(size_t)b * 4096 + p] = s;
}

// ---------------- bilinear-sample x_guide -> xgs[b][k][p] (bf16 channel-major) ----------------
// grid 4096 blocks (b x row x kquad), 256 thr = 4 waves x 64 px; 16 ch/thread, no LDS/barriers.
__global__ __launch_bounds__(256) void sampler_kernel(
    const float* __restrict__ xg, const float* __restrict__ coords,
    u16* __restrict__ xgs) {
  const int wg = blockIdx.x;
  const int id = (wg & 7) * 512 + (wg >> 3);  // XCD-chunked: adjacent rows same XCD
  const int kq = id >> 10;                    // 0..3 channel quad
  const int b = (id >> 6) & 15, row = id & 63;
  const int px = threadIdx.x & 63, ko = threadIdx.x >> 6;
  const int p = row * 64 + px;
  float2 cd = ((const float2*)coords)[(size_t)b * 4096 + p];
  float ix = cd.x, iy = cd.y;
  float x0f = floorf(ix), y0f = floorf(iy);
  int x0 = (int)x0f, y0 = (int)y0f;
  float wx1 = ix - x0f, wx0 = 1.f - wx1;
  float wy1 = iy - y0f, wy0 = 1.f - wy1;
  bool vx0 = (unsigned)x0 < 64u, vx1 = (unsigned)(x0 + 1) < 64u;
  bool vy0 = (unsigned)y0 < 64u, vy1 = (unsigned)(y0 + 1) < 64u;
  int x0c = min(max(x0, 0), 63), x1c = min(max(x0 + 1, 0), 63);
  int y0c = min(max(y0, 0), 63), y1c = min(max(y0 + 1, 0), 63);
  float w00 = (vx0 && vy0) ? wx0 * wy0 : 0.f;
  float w10 = (vx1 && vy0) ? wx1 * wy0 : 0.f;
  float w01 = (vx0 && vy1) ? wx0 * wy1 : 0.f;
  float w11 = (vx1 && vy1) ? wx1 * wy1 : 0.f;
  const int i00 = y0c * 64 + x0c, i10 = y0c * 64 + x1c;
  const int i01 = y1c * 64 + x0c, i11 = y1c * 64 + x1c;
  const int k0 = kq * 64 + ko * 16;
  const float* bb = xg + ((size_t)b * 256 + k0) * 4096;
  u16* xo = xgs + ((size_t)b * 256 + k0) * 4096 + p;
#pragma unroll
  for (int kk = 0; kk < 16; ++kk) {
    const float* bp = bb + (size_t)kk * 4096;
    float v = w00 * bp[i00] + w10 * bp[i10] + w01 * bp[i01] + w11 * bp[i11];
    xo[(size_t)kk * 4096] = f2bf(v);
  }
}

// ---------------- h GEMM: h = GELU(BN2(W1 @ x_local)) -> pixel-major bf16 ----------------
__global__ __launch_bounds__(256, 2) void gemm_h(
    const u16* __restrict__ A, const float* __restrict__ Bsrc,
    u16* __restrict__ Out, const float* __restrict__ bias) {
  __shared__ u16 Al[128][40];
  __shared__ u16 Bl[128][40];
  const int tid = threadIdx.x;
  const int b = blockIdx.y;
  const int n0 = blockIdx.x * 128;
  const int wave = tid >> 6, lane = tid & 63;
  const int wr = wave >> 1, wc = wave & 1;
  const int lr = lane & 15, kg = lane >> 4;
  f32x4 acc[4][4] = {};
  const float* Bf = Bsrc + (size_t)b * 256 * 4096;

  for (int kt = 0; kt < 8; ++kt) {
    {
      int m = tid >> 1, pos = (tid & 1) * 16;
      u16x8 v0 = *(const u16x8*)(A + (size_t)m * 256 + kt * 32 + pos);
      u16x8 v1 = *(const u16x8*)(A + (size_t)m * 256 + kt * 32 + pos + 8);
      *(u16x8*)&Al[m][pos] = v0;
      *(u16x8*)&Al[m][pos + 8] = v1;
    }
    {
      int nq = tid & 31, kq = tid >> 5;
      int kb = kt * 32 + kq * 4;
      int nb = n0 + nq * 4;
      f32x4 r[4];
#pragma unroll
      for (int i = 0; i < 4; ++i)
        r[i] = *(const f32x4*)(Bf + (size_t)(kb + i) * 4096 + nb);
#pragma unroll
      for (int j = 0; j < 4; ++j) {
        u16x4 w = {f2bf(r[0][j]), f2bf(r[1][j]), f2bf(r[2][j]), f2bf(r[3][j])};
        *(u16x4*)&Bl[nq * 4 + j][kq * 4] = w;
      }
    }
    __syncthreads();
    bf16x8 af[4], bfr[4];
#pragma unroll
    for (int i = 0; i < 4; ++i) {
      af[i] = *(const bf16x8*)&Al[wr * 64 + i * 16 + lr][kg * 8];
      bfr[i] = *(const bf16x8*)&Bl[wc * 64 + i * 16 + lr][kg * 8];
    }
#pragma unroll
    for (int i = 0; i < 4; ++i)
#pragma unroll
      for (int j = 0; j < 4; ++j)
        acc[i][j] = __builtin_amdgcn_mfma_f32_16x16x32_bf16(af[i], bfr[j], acc[i][j], 0, 0, 0);
    __syncthreads();
  }
  u16* O = Out + (size_t)b * 4096 * 128;
#pragma unroll
  for (int i = 0; i < 4; ++i) {
    int rb = wr * 64 + i * 16 + kg * 4;
    f32x4 b4 = *(const f32x4*)(bias + rb);
#pragma unroll
    for (int j = 0; j < 4; ++j) {
      int col = n0 + wc * 64 + j * 16 + lr;
      u16x4 w;
#pragma unroll
      for (int e = 0; e < 4; ++e) {
        float v = acc[i][j][e] + b4[e];
        v = 0.5f * v * (1.f + erff(v * 0.70710678118f));  // exact GELU
        w[e] = f2bf(v);
      }
      *(u16x4*)(O + (size_t)col * 128 + rb) = w;  // pixel-major
    }
  }
}

// ---------------- final fused GEMM: out = SiLU(Acat @ [xgs; h] + bias1*wsum) ----------------
__global__ __launch_bounds__(512, 2) void gemm_final(
    const u16* __restrict__ A,    // [256][384] bf16
    const u16* __restrict__ xgs,  // [b][256][4096] channel-major bf16
    const u16* __restrict__ hb,   // [b][4096][128] pixel-major bf16
    const float* __restrict__ bias1, const float* __restrict__ wsum,
    float* __restrict__ out) {
  __shared__ u16 Al[256][40];
  __shared__ u16 Bl[128][40];
  const int tid = threadIdx.x;
  const int b = blockIdx.y;
  const int n0 = blockIdx.x * 128;
  const int wave = tid >> 6, lane = tid & 63;
  const int wr = wave >> 1, wc = wave & 1;
  const int lr = lane & 15, kg = lane >> 4;
  f32x4 acc[4][4] = {};
  const u16* xb = xgs + (size_t)b * 256 * 4096;
  const u16* hp = hb + (size_t)b * 4096 * 128;

  for (int kt = 0; kt < 12; ++kt) {
#pragma unroll
    for (int c = 0; c < 2; ++c) {
      int ch = tid + c * 512;
      int m = ch >> 2, pos = (ch & 3) * 8;
      *(u16x8*)&Al[m][pos] = *(const u16x8*)(A + (size_t)m * 384 + kt * 32 + pos);
    }
    if (kt < 8) {
      int kq2 = tid >> 5;
      int nq = tid & 31;
      int k0 = kt * 32 + kq2 * 2;
      u16x4 r0 = *(const u16x4*)(xb + (size_t)k0 * 4096 + n0 + nq * 4);
      u16x4 r1 = *(const u16x4*)(xb + (size_t)(k0 + 1) * 4096 + n0 + nq * 4);
#pragma unroll
      for (int j = 0; j < 4; ++j) {
        u16x2 w = {r0[j], r1[j]};
        *(u16x2*)&Bl[nq * 4 + j][kq2 * 2] = w;
      }
    } else {
      int pl = tid >> 2, kq = tid & 3;
      *(u16x8*)&Bl[pl][kq * 8] =
          *(const u16x8*)(hp + (size_t)(n0 + pl) * 128 + (kt - 8) * 32 + kq * 8);
    }
    __syncthreads();
    bf16x8 af[4], bfr[4];
#pragma unroll
    for (int i = 0; i < 4; ++i) {
      af[i] = *(const bf16x8*)&Al[wr * 64 + i * 16 + lr][kg * 8];
      bfr[i] = *(const bf16x8*)&Bl[wc * 64 + i * 16 + lr][kg * 8];
    }
#pragma unroll
    for (int i = 0; i < 4; ++i)
#pragma unroll
      for (int j = 0; j < 4; ++j)
        acc[i][j] = __builtin_amdgcn_mfma_f32_16x16x32_bf16(af[i], bfr[j], acc[i][j], 0, 0, 0);
    __syncthreads();
  }

  float* Ob = out + (size_t)b * 256 * 4096;
#pragma unroll
  for (int j = 0; j < 4; ++j) {
    int col = n0 + wc * 64 + j * 16 + lr;
    float ws = wsum[(size_t)b * 4096 + col];
#pragma unroll
    for (int i = 0; i < 4; ++i) {
      int rb = wr * 64 + i * 16 + kg * 4;
      f32x4 b4 = *(const f32x4*)(bias1 + rb);
#pragma unroll
      for (int e = 0; e < 4; ++e) {
        float v = acc[i][j][e] + b4[e] * ws;  // sampled bias (zeros padding)
        Ob[(size_t)(rb + e) * 4096 + col] = v / (1.f + __expf(-v));  // SiLU
      }
    }
  }
}

// ---------------- launch ----------------
extern "C" void kernel_launch(void* const* d_in, const int* in_sizes, int n_in,
                              void* d_out, int out_size, void* d_ws, size_t ws_size,
                              hipStream_t stream) {
  const float* x_local = (const float*)d_in[0];
  const float* x_guide = (const float*)d_in[1];
  const float* w_align = (const float*)d_in[2];
  const float* bn1_g = (const float*)d_in[3];
  const float* bn1_b = (const float*)d_in[4];
  const float* bn1_m = (const float*)d_in[5];
  const float* bn1_v = (const float*)d_in[6];
  const float* w_off1 = (const float*)d_in[7];
  const float* w_off2 = (const float*)d_in[8];
  const float* b_off2 = (const float*)d_in[9];
  const float* w_mlp1 = (const float*)d_in[10];
  const float* bn2_g = (const float*)d_in[11];
  const float* bn2_b = (const float*)d_in[12];
  const float* bn2_m = (const float*)d_in[13];
  const float* bn2_v = (const float*)d_in[14];
  const float* w_mlp2 = (const float*)d_in[15];

  char* ws = (char*)d_ws;
  u16* Acat = (u16*)(ws + 0);               // 196608
  u16* w1_bf = (u16*)(ws + 196608);         // -> 262144
  float* bias1 = (float*)(ws + 262144);     // -> 263168
  float* bias2 = (float*)(ws + 263168);     // -> 263680
  float* wsum = (float*)(ws + 263680);      // 16*4096*4 -> 525824
  float* coords = (float*)(ws + 525824);    // 16*4096*8 -> 1050112
  u16* xgs = (u16*)(ws + 1050112);          // 33554432 -> 34604544
  u16* hbuf = (u16*)(ws + 34604544);        // 16777216 -> 51381760
  // sbuf (8.4 MB bf16) aliases hbuf: gconv writes it, coords+nothing else read it,
  // then gemm_h overwrites hbuf (stream-ordered liveness).
  u16* sbuf = hbuf;

  prep_weights<<<256, 384, 0, stream>>>(
      w_align, bn1_g, bn1_b, bn1_m, bn1_v,
      w_mlp1, bn2_g, bn2_b, bn2_m, bn2_v, w_mlp2,
      Acat, w1_bf, bias1, bias2);

  gconv_kernel<<<dim3(4, 64, 16), 256, 0, stream>>>(x_local, w_off1, sbuf);

  coords_kernel<<<dim3(16, 16), 256, 0, stream>>>(sbuf, w_off2, b_off2, coords, wsum);

  sampler_kernel<<<4096, 256, 0, stream>>>(x_guide, coords, xgs);

  gemm_h<<<dim3(32, 16), 256, 0, stream>>>(w1_bf, x_local, hbuf, bias2);

  gemm_final<<<dim3(32, 16), 512, 0, stream>>>(Acat, xgs, hbuf, bias1, wsum, (float*)d_out);
}